// Round 6
// baseline (194.014 us; speedup 1.0000x reference)
//
#include <hip/hip_runtime.h>
#include <hip/hip_bf16.h>

// ---------------------------------------------------------------------------
// GNN action-value net, MI355X. Round 17: revert R16 regressions + wide prep.
//  * R16 post-mortem: entry prefetch = warm +12us (pure added work), NT
//    stores = +7MB write amp. Both reverted. Bench unmoved -> bench is
//    dominated by launch-after-idle (poison fill runs at 8.6 GB/s = idle
//    clocks; DVFS ramp ~100us weakly coupled to kernel cycles).
//  * This round: (1) graph_kernel = R15 structure exactly (best verified:
//    8 raw lgkmcnt barriers, Pf swizzle, 512thr, (512,6), 53.5KB LDS);
//    (2) prep widened 91 -> 1024 blocks (~1 elem/thread: all CUs busy
//    during the clock ramp instead of 9%); (3) 660 spare prep blocks
//    pre-stream graph inputs (ei/ea/nedg/x ~14MB) into L2/L3 so the cold
//    graph dispatch's per-block entry loads hit cache.
// Fragment maps (verified r5-r10): A[m][k]: m=lane&15, k=(lane>>4)*8+j;
// B[k][n]: n=lane&15, k=(lane>>4)*8+j; C/D: col=lane&15, row=(lane>>4)*4+reg.
// ---------------------------------------------------------------------------

#define NPG 64
#define EPG 1024
#define NEPG 256
#define B_GR 1024
#define E_TOT 1048576
#define EMB 64
#define HID 128
#define NOUT 101
#define OUT_PG 6721            // 1 + 64*101 + 256

typedef __attribute__((ext_vector_type(8))) short bf16x8;
typedef __attribute__((ext_vector_type(4))) float f32x4;
typedef unsigned short ushort_t;

__device__ __align__(16) ushort_t g_nt1[100*HID];   // bf16 rows: node_tab @ c1_w
__device__ __align__(16) ushort_t g_c2w[HID*HID];   // frag-packed bf16
__device__ __align__(16) ushort_t g_nw1[HID*HID];
__device__ __align__(16) ushort_t g_ew1[HID*HID];
__device__ __align__(16) ushort_t g_nw2[HID*112];   // N padded 101 -> 112
__device__ __align__(16) float    g_sw1t[HID*HID];  // s_w1 transposed, f32
__device__ __align__(16) float    g_hs1[128], g_hd1[128];  // per-cat attn scalars
__device__ __align__(16) float    g_he1[4], g_he2[4];

__device__ __forceinline__ ushort_t f2bf(float f) {
  unsigned u = __float_as_uint(f);
  return (ushort_t)((u + 0x7fffu + ((u >> 16) & 1u)) >> 16);
}
__device__ __forceinline__ float bf2f(ushort_t h) {
  return __uint_as_float(((unsigned)h) << 16);
}
__device__ __forceinline__ unsigned pk2(float a, float b) {
  __hip_bfloat162 h = __float22bfloat162_rn(make_float2(a, b));
  unsigned r; __builtin_memcpy(&r, &h, 4); return r;
}
__device__ __forceinline__ bf16x8 pk8(float4 v0, float4 v1) {
  union { bf16x8 v; unsigned u[4]; } o;
  o.u[0] = pk2(v0.x, v0.y); o.u[1] = pk2(v0.z, v0.w);
  o.u[2] = pk2(v1.x, v1.y); o.u[3] = pk2(v1.z, v1.w);
  return o.v;
}
// Pf swizzle: float4-slot index XORed with row&15. Bijective per row;
// spreads the agg preload and edge atomics over all bank groups.
__device__ __forceinline__ int pf_idx(int d, int s) {
  return d*64 + ((((s >> 2) ^ d) & 15) << 2) + (s & 3);
}
// Raw LDS-only barrier: no vmcnt drain (no cross-thread global comms).
__device__ __forceinline__ void bar_lds() {
  asm volatile("s_waitcnt lgkmcnt(0)" ::: "memory");
  __builtin_amdgcn_s_barrier();
  asm volatile("" ::: "memory");
}

// ---------------------------------------------------------------------------
// prep: 1024 blocks x 256 threads (~1 table elem per thread -> all CUs busy
// during the post-idle clock ramp).
//  b0: logit consts. b1: hs1/hd1. b2-51: nt1. b52-115: c2w. b116-179: nw1.
//  b180-243: ew1. b244-299: nw2. b300-363: sw1t.
//  b364-1023: pre-stream graph inputs (ei/ea/nedg/x) into L2/L3.
__global__ void prep_kernel(
    const float* __restrict__ node_tab, const float* __restrict__ edge_tab,
    const float* __restrict__ c1_w,  const float* __restrict__ c1_we,
    const float* __restrict__ c1_as, const float* __restrict__ c1_ad,
    const float* __restrict__ c1_ae,
    const float* __restrict__ c2_w,  const float* __restrict__ c2_we,
    const float* __restrict__ c2_ae,
    const float* __restrict__ s_w1,  const float* __restrict__ n_w1,
    const float* __restrict__ n_w2,  const float* __restrict__ e_w1,
    const int* __restrict__ ei, const int* __restrict__ ea,
    const int* __restrict__ nedg, const int* __restrict__ x)
{
  const int b = blockIdx.x, tid = threadIdx.x;
  if (b == 0) {                       // per-edge-type logit constants
    __shared__ float v1[EMB], v2[EMB];
    if (tid < EMB) {
      float a = 0.f, d = 0.f;
      for (int j = 0; j < HID; ++j) {
        a = fmaf(c1_we[tid*HID + j], c1_ae[j], a);
        d = fmaf(c2_we[tid*HID + j], c2_ae[j], d);
      }
      v1[tid] = a; v2[tid] = d;
    }
    __syncthreads();
    if (tid < 4) {
      float a = 0.f, d = 0.f;
      for (int k = 0; k < EMB; ++k) {
        const float ev = edge_tab[tid*EMB + k];
        a = fmaf(ev, v1[k], a); d = fmaf(ev, v2[k], d);
      }
      g_he1[tid] = a; g_he2[tid] = d;
    }
    return;
  }
  if (b == 1) {                       // per-category attention scalars
    __shared__ float vs[EMB], vd[EMB];
    if (tid < EMB) {
      float a = 0.f, d = 0.f;
      for (int j = 0; j < HID; ++j) {
        const float w = c1_w[tid*HID + j];
        a = fmaf(w, c1_as[j], a); d = fmaf(w, c1_ad[j], d);
      }
      vs[tid] = a; vd[tid] = d;
    }
    __syncthreads();
    if (tid < 128) {
      float a = 0.f, d = 0.f;
      if (tid < 100) {
        for (int k = 0; k < EMB; ++k) {
          const float xv = node_tab[tid*EMB + k];
          a = fmaf(xv, vs[k], a); d = fmaf(xv, vd[k], d);
        }
      }
      g_hs1[tid] = a; g_hd1[tid] = d;
    }
    return;
  }
  if (b <= 51) {                      // nt1 = node_tab @ c1_w (100x128)
    const int idx = (b - 2) * 256 + tid;
    const int i = idx >> 7, j = idx & (HID - 1);
    float s = 0.f;
    #pragma unroll 8
    for (int k = 0; k < EMB; ++k) s = fmaf(node_tab[i*EMB + k], c1_w[k*HID + j], s);
    g_nt1[idx] = f2bf(s);
    return;
  }
  if (b <= 243) {                     // c2w / nw1 / ew1: 16384 each, 64 blk
    const int grp = (b - 52) >> 6;
    const int idx = ((b - 52) & 63) * 256 + tid;
    const float* W = (grp == 0) ? c2_w : (grp == 1) ? n_w1 : e_w1;
    ushort_t* G = (grp == 0) ? g_c2w : (grp == 1) ? g_nw1 : g_ew1;
    const int j = idx & 7, l = (idx >> 3) & 63, r2 = idx >> 9;
    const int ks = r2 & 3, ct = r2 >> 2;
    const int row = ks*32 + (l >> 4)*8 + j;
    const int col = ct*16 + (l & 15);
    G[idx] = f2bf(W[row*HID + col]);
    return;
  }
  if (b <= 299) {                     // nw2: 14336, 56 blocks
    const int idx = (b - 244) * 256 + tid;
    const int j = idx & 7, l = (idx >> 3) & 63, r2 = idx >> 9;
    const int ks = r2 & 3, ct = r2 >> 2;
    const int row = ks*32 + (l >> 4)*8 + j;
    const int col = ct*16 + (l & 15);
    g_nw2[idx] = (col < NOUT) ? f2bf(n_w2[row*NOUT + col]) : (ushort_t)0;
    return;
  }
  if (b <= 363) {                     // sw1t: 16384, 64 blocks
    const int idx = (b - 300) * 256 + tid;
    g_sw1t[idx] = s_w1[(idx & 127)*HID + (idx >> 7)];
    return;
  }
  {                                   // input pre-stream: 660 blocks
    const int i = (b - 364) * 256 + tid;        // [0, 168960)
    unsigned snk = 0;
    const uint4* pei = (const uint4*)ei;        // 2M ints = 524288 uint4
    #pragma unroll
    for (int p = 0; p < 4; ++p) {
      const int k = i + p*168960;
      if (k < 524288) { uint4 v = pei[k]; snk ^= v.x^v.y^v.z^v.w; }
    }
    const uint4* pea = (const uint4*)ea;        // 1M ints = 262144 uint4
    #pragma unroll
    for (int p = 0; p < 2; ++p) {
      const int k = i + p*168960;
      if (k < 262144) { uint4 v = pea[k]; snk ^= v.x^v.y^v.z^v.w; }
    }
    const uint4* pne = (const uint4*)nedg;      // 512K ints = 131072 uint4
    if (i < 131072) { uint4 v = pne[i]; snk ^= v.x^v.y^v.z^v.w; }
    const uint4* px = (const uint4*)x;          // 64K ints = 16384 uint4
    if (i < 16384) { uint4 v = px[i]; snk ^= v.x^v.y^v.z^v.w; }
    asm volatile("" :: "v"(snk));
  }
}

// ---------------------------------------------------------------------------
// LDS map (bytes). Pf de-overlaid from Hr.
// Tail: part(2KB) + ebw(1KB) overlay dead Pf (Pf last read before B6).
#define S_HC   0        // Hc 128x72 ushort feat-major; reused as a1b rows
#define S_PF   18432    // Pf 64x64 f32 swizzled (16384)
#define S_HR   34816    // Hr 64 rows stride 136 ushort (17408)
#define S_NS   52224    // 64 f32
#define S_ND   52480    // 64 f32
#define S_GP   52736    // 128 f32
#define S_HCC  53248    // 8 f32
#define S_XS   53280    // 64 int
#define S_TOT  53536    // 3 blocks/CU (3x <= 160KB)

__global__ __launch_bounds__(512, 6) void graph_kernel(
    const float* __restrict__ c1_b,
    const float* __restrict__ c2_as, const float* __restrict__ c2_ad,
    const float* __restrict__ c2_b,
    const float* __restrict__ s_b1,  const float* __restrict__ s_w2,
    const float* __restrict__ s_b2,
    const float* __restrict__ n_b1,  const float* __restrict__ n_b2,
    const float* __restrict__ e_b1,  const float* __restrict__ e_w2,
    const float* __restrict__ e_b2,
    const int* __restrict__ x,  const int* __restrict__ ei,
    const int* __restrict__ ea, const int* __restrict__ nedg,
    float* __restrict__ out)
{
  const int tid = threadIdx.x;
  const int gid = blockIdx.x;
  const int nb = gid * NPG;
  const int lane = tid & 63;
  const int wv = tid >> 6;         // 0..7
  const int wr = wv & 3;           // row-group
  const int ch = wv >> 2;          // col-half (ct in [ch*4, ch*4+4))
  const int qd = lane >> 4;        // quad
  const int cl = lane & 15;        // col/row-in-tile
  const int rb = wr * 16;          // wave's M-tile base row

  __shared__ __align__(16) char smem[S_TOT];
  ushort_t* Hc   = (ushort_t*)(smem + S_HC);   // [feat*72 + node]
  float*    Pf   = (float*)   (smem + S_PF);   // 64x64 f32 (swizzled)
  ushort_t* Hr   = (ushort_t*)(smem + S_HR);   // stride 136 (row-major)
  float*    part = (float*)   (smem + S_PF);          // tail overlay
  float*    ebw  = (float*)   (smem + S_PF + 2048);   // tail overlay
  float*    ns   = (float*)   (smem + S_NS);
  float*    nd   = (float*)   (smem + S_ND);
  float*    gp   = (float*)   (smem + S_GP);
  float*    hc   = (float*)   (smem + S_HCC);
  int*      xs   = (int*)     (smem + S_XS);
  ushort_t* a1b  = Hc;                         // 64x136 rows

  // ---- SEG0: input loads (longest dep-chain first), init ----
  const int cat = (tid < NPG) ? x[nb + tid] : 0;   // x -> g_hs1 chain, earliest
  unsigned er[2];
  #pragma unroll
  for (int i = 0; i < 2; ++i) {
    const int k = tid + 512*i;
    const int s = ei[gid*EPG + k] - nb;
    const int d = ei[E_TOT + gid*EPG + k] - nb;
    const int t = ea[gid*EPG + k];
    er[i] = (unsigned)(s | (d << 6) | (t << 12));
  }
  const int2 prr = *(const int2*)(nedg + 2*(gid*NEPG + (tid >> 1)));

  if (tid < NPG) {
    xs[tid] = cat;
    ns[tid] = g_hs1[cat];
    nd[tid] = g_hd1[cat];
  }
  {
    float4* pz = (float4*)Pf;
    pz[tid]       = make_float4(0.f,0.f,0.f,0.f);
    pz[tid + 512] = make_float4(0.f,0.f,0.f,0.f);
  }
  if (tid < 128) gp[tid] = 0.f;
  if (tid < 8) hc[tid] = (tid < 4) ? g_he1[tid] : g_he2[tid-4];
  bar_lds();                                              // B1

  // ---- SEG1: layer-1 edge pass (atomics) overlapped with nt1->Hc gather ----
  {
    const int f0 = wv * 16;
    const ushort_t* srcp = g_nt1 + xs[lane]*HID + f0;
    const bf16x8 t0 = ((const bf16x8*)srcp)[0];
    const bf16x8 t1 = ((const bf16x8*)srcp)[1];
    #pragma unroll
    for (int i = 0; i < 2; ++i) {
      const unsigned tp = er[i];
      const int s = tp & 63, d = (tp >> 6) & 63, t = tp >> 12;
      float l = ns[s] + nd[d] + hc[t];
      l = (l > 0.f) ? l : 0.2f * l;
      atomicAdd(&Pf[pf_idx(d, s)], __expf(l));
    }
    #pragma unroll
    for (int q = 0; q < 8; ++q) {
      Hc[(f0 +     q)*72 + lane] = (ushort_t)t0[q];
      Hc[(f0 + 8 + q)*72 + lane] = (ushort_t)t1[q];
    }
  }
  bar_lds();                                              // B2

  // ---- SEG2: Pf preload + den + ns/nd clear + agg1 MFMA -> Hr ----
  {
    bf16x8 pa0, pa1;
    float inv4[4];
    const float* pr = Pf + (rb + cl)*64;
    const float4 v0 = *(const float4*)(pr + (((2*qd    ) ^ cl) << 2));
    const float4 v1 = *(const float4*)(pr + (((2*qd + 1) ^ cl) << 2));
    const float4 v2 = *(const float4*)(pr + (((2*qd + 8) ^ cl) << 2));
    const float4 v3 = *(const float4*)(pr + (((2*qd + 9) ^ cl) << 2));
    pa0 = pk8(v0, v1); pa1 = pk8(v2, v3);
    float den = v0.x+v0.y+v0.z+v0.w + v1.x+v1.y+v1.z+v1.w
              + v2.x+v2.y+v2.z+v2.w + v3.x+v3.y+v3.z+v3.w;
    den += __shfl_xor(den, 16, 64);
    den += __shfl_xor(den, 32, 64);
    #pragma unroll
    for (int r = 0; r < 4; ++r)
      inv4[r] = 1.f / (__shfl(den, qd*4 + r, 64) + 1e-16f);
    if (tid < NPG) { ns[tid] = 0.f; nd[tid] = 0.f; }   // for SEG3 atomics
    #pragma unroll
    for (int i = 0; i < 4; ++i) {
      const int ct = ch*4 + i;
      f32x4 acc = {0.f, 0.f, 0.f, 0.f};
      const bf16x8 b0 = *(const bf16x8*)(Hc + (ct*16+cl)*72 + qd*8);
      const bf16x8 b1 = *(const bf16x8*)(Hc + (ct*16+cl)*72 + 32 + qd*8);
      acc = __builtin_amdgcn_mfma_f32_16x16x32_bf16(pa0, b0, acc, 0, 0, 0);
      acc = __builtin_amdgcn_mfma_f32_16x16x32_bf16(pa1, b1, acc, 0, 0, 0);
      const int n = ct*16 + cl;
      const float bias = c1_b[n];
      #pragma unroll
      for (int r = 0; r < 4; ++r)
        Hr[(rb + qd*4 + r)*136 + n] = f2bf(fmaxf(fmaf(acc[r], inv4[r], bias), 0.f));
    }
  }
  bar_lds();                                              // B3

  // ---- SEG3: h1f load + Pf re-zero + P7 (h2pre = h1 @ c2_w) + ns/nd ----
  {
    bf16x8 h1f[4];
    #pragma unroll
    for (int ks = 0; ks < 4; ++ks)
      h1f[ks] = *(const bf16x8*)(Hr + (rb+cl)*136 + ks*32 + qd*8);
    float4* pz = (float4*)Pf;
    pz[tid]       = make_float4(0.f,0.f,0.f,0.f);
    pz[tid + 512] = make_float4(0.f,0.f,0.f,0.f);
    float pns[4] = {0.f,0.f,0.f,0.f}, pnd[4] = {0.f,0.f,0.f,0.f};
    #pragma unroll
    for (int i = 0; i < 4; ++i) {
      const int ct = ch*4 + i;
      f32x4 acc = {0.f, 0.f, 0.f, 0.f};
      #pragma unroll
      for (int ks = 0; ks < 4; ++ks) {
        const bf16x8 b = *(const bf16x8*)(g_c2w + ((ct*4+ks)*64 + lane)*8);
        acc = __builtin_amdgcn_mfma_f32_16x16x32_bf16(h1f[ks], b, acc, 0, 0, 0);
      }
      const int n = ct*16 + cl;
      const float asv = c2_as[n], adv = c2_ad[n];
      uint2 pkd;                       // rows rb+qd*4 .. +3 are consecutive
      pkd.x = pk2(acc[0], acc[1]);
      pkd.y = pk2(acc[2], acc[3]);
      *(uint2*)&Hc[n*72 + rb + qd*4] = pkd;
      #pragma unroll
      for (int r = 0; r < 4; ++r) {
        pns[r] = fmaf(acc[r], asv, pns[r]);
        pnd[r] = fmaf(acc[r], adv, pnd[r]);
      }
    }
    #pragma unroll
    for (int r = 0; r < 4; ++r) {
      #pragma unroll
      for (int off = 1; off < 16; off <<= 1) {
        pns[r] += __shfl_xor(pns[r], off, 64);
        pnd[r] += __shfl_xor(pnd[r], off, 64);
      }
    }
    if (cl == 0) {
      #pragma unroll
      for (int r = 0; r < 4; ++r) {
        atomicAdd(&ns[rb + qd*4 + r], pns[r]);
        atomicAdd(&nd[rb + qd*4 + r], pnd[r]);
      }
    }
  }
  bar_lds();                                              // B4

  // ---- SEG4: edge pass 2 ----
  #pragma unroll
  for (int i = 0; i < 2; ++i) {
    const unsigned tp = er[i];
    const int s = tp & 63, d = (tp >> 6) & 63, t = tp >> 12;
    float l = ns[s] + nd[d] + hc[4 + t];
    l = (l > 0.f) ? l : 0.2f * l;
    atomicAdd(&Pf[pf_idx(d, s)], __expf(l));
  }
  bar_lds();                                              // B5

  // ---- SEG5: Pf preload2 + den + agg2 MFMA -> Hr + pooling ----
  {
    bf16x8 pa0, pa1;
    float inv4[4];
    const float* pr = Pf + (rb + cl)*64;
    const float4 v0 = *(const float4*)(pr + (((2*qd    ) ^ cl) << 2));
    const float4 v1 = *(const float4*)(pr + (((2*qd + 1) ^ cl) << 2));
    const float4 v2 = *(const float4*)(pr + (((2*qd + 8) ^ cl) << 2));
    const float4 v3 = *(const float4*)(pr + (((2*qd + 9) ^ cl) << 2));
    pa0 = pk8(v0, v1); pa1 = pk8(v2, v3);
    float den = v0.x+v0.y+v0.z+v0.w + v1.x+v1.y+v1.z+v1.w
              + v2.x+v2.y+v2.z+v2.w + v3.x+v3.y+v3.z+v3.w;
    den += __shfl_xor(den, 16, 64);
    den += __shfl_xor(den, 32, 64);
    #pragma unroll
    for (int r = 0; r < 4; ++r)
      inv4[r] = 1.f / (__shfl(den, qd*4 + r, 64) + 1e-16f);
    #pragma unroll
    for (int i = 0; i < 4; ++i) {
      const int ct = ch*4 + i;
      f32x4 acc = {0.f, 0.f, 0.f, 0.f};
      const bf16x8 b0 = *(const bf16x8*)(Hc + (ct*16+cl)*72 + qd*8);
      const bf16x8 b1 = *(const bf16x8*)(Hc + (ct*16+cl)*72 + 32 + qd*8);
      acc = __builtin_amdgcn_mfma_f32_16x16x32_bf16(pa0, b0, acc, 0, 0, 0);
      acc = __builtin_amdgcn_mfma_f32_16x16x32_bf16(pa1, b1, acc, 0, 0, 0);
      const int n = ct*16 + cl;
      const float bias = c2_b[n];
      float colsum = 0.f;
      #pragma unroll
      for (int r = 0; r < 4; ++r) {
        const float v = fmaf(acc[r], inv4[r], bias);
        Hr[(rb + qd*4 + r)*136 + n] = f2bf(v);
        colsum += v;
      }
      colsum += __shfl_xor(colsum, 16, 64);
      colsum += __shfl_xor(colsum, 32, 64);
      if (qd == 0) atomicAdd(&gp[n], colsum);
    }
  }
  bar_lds();                                              // B6

  // ---- SEG6: stop partials (Pf dead -> part/ebw overlay) + h2f hoist ----
  {
    const int j = tid & 127, c = tid >> 7;
    const float* wrp = g_sw1t + j*HID + c*32;
    const float* grp = gp + c*32;
    float p = 0.f;
    #pragma unroll
    for (int q = 0; q < 8; ++q) {
      const float4 w = ((const float4*)wrp)[q];
      const float4 g = ((const float4*)grp)[q];
      p = fmaf(w.x, g.x, p); p = fmaf(w.y, g.y, p);
      p = fmaf(w.z, g.z, p); p = fmaf(w.w, g.w, p);
    }
    part[tid] = p;
  }
  if (tid < 256) ebw[tid] = (tid < 128) ? e_b1[tid] : e_w2[tid - 128];
  bf16x8 h2f[4];
  #pragma unroll
  for (int ks = 0; ks < 4; ++ks)
    h2f[ks] = *(const bf16x8*)(Hr + (rb+cl)*136 + ks*32 + qd*8);
  bar_lds();                                              // B7

  // ---- SEG7: stop reduce (wave 0) + fused addnode/addedge staging ----
  if (tid < 64) {
    const float d0 = part[tid]    + part[tid+128] + part[tid+256] + part[tid+384];
    const float d1 = part[tid+64] + part[tid+192] + part[tid+320] + part[tid+448];
    const float z0 = fmaxf(d0 + s_b1[tid], 0.f);
    const float z1 = fmaxf(d1 + s_b1[tid+64], 0.f);
    float p = fmaf(z0, s_w2[tid], z1 * s_w2[tid+64]);
    #pragma unroll
    for (int off = 32; off > 0; off >>= 1) p += __shfl_down(p, off, 64);
    if (tid == 0) out[(size_t)gid*OUT_PG] = p + s_b2[0];
  }
  {
    #pragma unroll
    for (int i = 0; i < 4; ++i) {
      const int ct = ch*4 + i;
      f32x4 an  = {0.f, 0.f, 0.f, 0.f};
      f32x4 ae2 = {0.f, 0.f, 0.f, 0.f};
      #pragma unroll
      for (int ks = 0; ks < 4; ++ks) {
        const bf16x8 bn = *(const bf16x8*)(g_nw1 + ((ct*4+ks)*64 + lane)*8);
        const bf16x8 be = *(const bf16x8*)(g_ew1 + ((ct*4+ks)*64 + lane)*8);
        an  = __builtin_amdgcn_mfma_f32_16x16x32_bf16(h2f[ks], bn, an, 0, 0, 0);
        ae2 = __builtin_amdgcn_mfma_f32_16x16x32_bf16(h2f[ks], be, ae2, 0, 0, 0);
      }
      const int n = ct*16 + cl;
      const float bias = n_b1[n];
      #pragma unroll
      for (int r = 0; r < 4; ++r) {
        a1b[(rb + qd*4 + r)*136 + n] = f2bf(fmaxf(an[r] + bias, 0.f));
        Hr[(rb + qd*4 + r)*136 + n] = f2bf(ae2[r]);
      }
    }
  }
  bar_lds();                                              // B8

  // ---- SEG8: addedge pairs + addnode head (LDS-read-only, no barrier) ----
  {
    const int pi = tid >> 1, hf = tid & 1;
    const ushort_t* ui = Hr + (prr.x - nb)*136 + hf*64;
    const ushort_t* uj = Hr + (prr.y - nb)*136 + hf*64;
    float ssum = 0.f;
    #pragma unroll
    for (int q8 = 0; q8 < 8; ++q8) {
      const bf16x8 va = *(const bf16x8*)(ui + q8*8);
      const bf16x8 vb = *(const bf16x8*)(uj + q8*8);
      #pragma unroll
      for (int j = 0; j < 8; ++j) {
        const int c = hf*64 + q8*8 + j;
        float v = bf2f((ushort_t)va[j]) + bf2f((ushort_t)vb[j]) + ebw[c];
        v = fmaxf(v, 0.f);
        ssum = fmaf(v, ebw[128 + c], ssum);
      }
    }
    ssum += __shfl_xor(ssum, 1, 64);
    if (hf == 0)
      out[(size_t)gid*OUT_PG + 1 + NPG*NOUT + pi] = ssum + e_b2[0];
  }
  {
    bf16x8 af[4];
    #pragma unroll
    for (int ks = 0; ks < 4; ++ks)
      af[ks] = *(const bf16x8*)(a1b + (rb+cl)*136 + ks*32 + qd*8);
    float* ob = out + (size_t)gid*OUT_PG + 1;
    #pragma unroll
    for (int i = 0; i < 4; ++i) {
      const int ct = ch*4 + i;
      if (ct < 7) {
        f32x4 acc = {0.f, 0.f, 0.f, 0.f};
        #pragma unroll
        for (int ks = 0; ks < 4; ++ks) {
          const bf16x8 b = *(const bf16x8*)(g_nw2 + ((ct*4+ks)*64 + lane)*8);
          acc = __builtin_amdgcn_mfma_f32_16x16x32_bf16(af[ks], b, acc, 0, 0, 0);
        }
        const int o = ct*16 + cl;
        if (o < NOUT) {
          const float b2 = n_b2[o];
          #pragma unroll
          for (int r = 0; r < 4; ++r)
            ob[(size_t)(rb + qd*4 + r)*NOUT + o] = acc[r] + b2;
        }
      }
    }
  }
}

// ---------------------------------------------------------------------------
extern "C" void kernel_launch(void* const* d_in, const int* in_sizes, int n_in,
                              void* d_out, int out_size, void* d_ws, size_t ws_size,
                              hipStream_t stream) {
  const float* node_tab = (const float*)d_in[0];
  const float* edge_tab = (const float*)d_in[1];
  const float* c1_w  = (const float*)d_in[2];
  const float* c1_we = (const float*)d_in[3];
  const float* c1_as = (const float*)d_in[4];
  const float* c1_ad = (const float*)d_in[5];
  const float* c1_ae = (const float*)d_in[6];
  const float* c1_b  = (const float*)d_in[7];
  const float* c2_w  = (const float*)d_in[8];
  const float* c2_we = (const float*)d_in[9];
  const float* c2_as = (const float*)d_in[10];
  const float* c2_ad = (const float*)d_in[11];
  const float* c2_ae = (const float*)d_in[12];
  const float* c2_b  = (const float*)d_in[13];
  const float* s_w1  = (const float*)d_in[14];
  const float* s_b1  = (const float*)d_in[15];
  const float* s_w2  = (const float*)d_in[16];
  const float* s_b2  = (const float*)d_in[17];
  const float* n_w1  = (const float*)d_in[18];
  const float* n_b1  = (const float*)d_in[19];
  const float* n_w2  = (const float*)d_in[20];
  const float* n_b2  = (const float*)d_in[21];
  const float* e_w1  = (const float*)d_in[22];
  const float* e_b1  = (const float*)d_in[23];
  const float* e_w2  = (const float*)d_in[24];
  const float* e_b2  = (const float*)d_in[25];
  const int* x    = (const int*)d_in[26];
  const int* ei   = (const int*)d_in[27];
  const int* ea   = (const int*)d_in[28];
  const int* nedg = (const int*)d_in[29];
  float* out = (float*)d_out;

  prep_kernel<<<dim3(1024), dim3(256), 0, stream>>>(
      node_tab, edge_tab, c1_w, c1_we, c1_as, c1_ad, c1_ae,
      c2_w, c2_we, c2_ae, s_w1, n_w1, n_w2, e_w1, ei, ea, nedg, x);

  graph_kernel<<<dim3(B_GR), dim3(512), 0, stream>>>(
      c1_b, c2_as, c2_ad, c2_b, s_b1, s_w2, s_b2,
      n_b1, n_b2, e_b1, e_w2, e_b2, x, ei, ea, nedg, out);
}

// Round 7
// 186.205 us; speedup vs baseline: 1.0419x; 1.0419x over previous
//
#include <hip/hip_runtime.h>
#include <hip/hip_bf16.h>

// ---------------------------------------------------------------------------
// GNN action-value net, MI355X. Round 18: full revert to the best-measured
// configuration (R0/R11 kernel, bench 184.75us).
//  * R12-R17 post-mortem: seven rounds of structural levers (occupancy
//    36/47/65%, spill elimination, output coalescing, barrier count 11->8,
//    vmcnt-free barriers, cold-cache prefetch, NT stores, wide prep, input
//    pre-stream) ALL neutral-to-negative on the bench metric while warm
//    dispatch stayed ~61us. Bench = cold dispatch + ~120us fixed cost
//    (launch-after-idle DVFS ramp + cold-HBM fill), insensitive to kernel
//    structure. Best bench on record = this exact source. Reverted.
// Fragment maps (verified r5-r10): A[m][k]: m=lane&15, k=(lane>>4)*8+j;
// B[k][n]: n=lane&15, k=(lane>>4)*8+j; C/D: col=lane&15, row=(lane>>4)*4+reg.
// ---------------------------------------------------------------------------

#define NPG 64
#define EPG 1024
#define NEPG 256
#define B_GR 1024
#define E_TOT 1048576
#define EMB 64
#define HID 128
#define NOUT 101
#define OUT_PG 6721            // 1 + 64*101 + 256

typedef __attribute__((ext_vector_type(8))) short bf16x8;
typedef __attribute__((ext_vector_type(4))) float f32x4;
typedef unsigned short ushort_t;

__device__ ushort_t g_nt1[100*HID];      // bf16 rows: node_tab @ c1_w
__device__ ushort_t g_c2w[HID*HID];      // frag-packed bf16
__device__ ushort_t g_nw1[HID*HID];
__device__ ushort_t g_ew1[HID*HID];
__device__ ushort_t g_nw2[HID*112];      // N padded 101 -> 112
__device__ float    g_sw1t[HID*HID];     // s_w1 transposed, f32
__device__ float    g_hs1[128], g_hd1[128];   // per-category attn scalars
__device__ float    g_he1[4], g_he2[4];

__device__ __forceinline__ ushort_t f2bf(float f) {
  unsigned u = __float_as_uint(f);
  return (ushort_t)((u + 0x7fffu + ((u >> 16) & 1u)) >> 16);
}
__device__ __forceinline__ float bf2f(ushort_t h) {
  return __uint_as_float(((unsigned)h) << 16);
}
__device__ __forceinline__ unsigned pk2(float a, float b) {
  __hip_bfloat162 h = __float22bfloat162_rn(make_float2(a, b));
  unsigned r; __builtin_memcpy(&r, &h, 4); return r;
}
__device__ __forceinline__ bf16x8 pk8(float4 v0, float4 v1) {
  union { bf16x8 v; unsigned u[4]; } o;
  o.u[0] = pk2(v0.x, v0.y); o.u[1] = pk2(v0.z, v0.w);
  o.u[2] = pk2(v1.x, v1.y); o.u[3] = pk2(v1.z, v1.w);
  return o.v;
}

// ---------------------------------------------------------------------------
// prep: 91 blocks. b0: logit consts. b1-50: nt1. b51: hs1/hd1.
// b52-75: c2w/nw1/ew1. b76-82: nw2. b83-90: sw1t.
__global__ void prep_kernel(
    const float* __restrict__ node_tab, const float* __restrict__ edge_tab,
    const float* __restrict__ c1_w,  const float* __restrict__ c1_we,
    const float* __restrict__ c1_as, const float* __restrict__ c1_ad,
    const float* __restrict__ c1_ae,
    const float* __restrict__ c2_w,  const float* __restrict__ c2_we,
    const float* __restrict__ c2_ae,
    const float* __restrict__ s_w1,  const float* __restrict__ n_w1,
    const float* __restrict__ n_w2,  const float* __restrict__ e_w1)
{
  const int b = blockIdx.x, tid = threadIdx.x;
  if (b == 0) {                       // per-edge-type logit constants
    __shared__ float v1[EMB], v2[EMB];
    if (tid < EMB) {
      float a = 0.f, d = 0.f;
      for (int j = 0; j < HID; ++j) {
        a = fmaf(c1_we[tid*HID + j], c1_ae[j], a);
        d = fmaf(c2_we[tid*HID + j], c2_ae[j], d);
      }
      v1[tid] = a; v2[tid] = d;
    }
    __syncthreads();
    if (tid < 4) {
      float a = 0.f, d = 0.f;
      for (int k = 0; k < EMB; ++k) {
        const float ev = edge_tab[tid*EMB + k];
        a = fmaf(ev, v1[k], a); d = fmaf(ev, v2[k], d);
      }
      g_he1[tid] = a; g_he2[tid] = d;
    }
    return;
  }
  if (b <= 50) {                      // nt1 = node_tab @ c1_w (100x128)
    const int idx = (b - 1) * 256 + tid;
    const int i = idx >> 7, j = idx & (HID - 1);
    float s = 0.f;
    #pragma unroll 8
    for (int k = 0; k < EMB; ++k) s = fmaf(node_tab[i*EMB + k], c1_w[k*HID + j], s);
    g_nt1[idx] = f2bf(s);
    return;
  }
  if (b == 51) {                      // per-category attention scalars
    __shared__ float vs[EMB], vd[EMB];
    if (tid < EMB) {
      float a = 0.f, d = 0.f;
      for (int j = 0; j < HID; ++j) {
        const float w = c1_w[tid*HID + j];
        a = fmaf(w, c1_as[j], a); d = fmaf(w, c1_ad[j], d);
      }
      vs[tid] = a; vd[tid] = d;
    }
    __syncthreads();
    if (tid < 128) {
      float a = 0.f, d = 0.f;
      if (tid < 100) {
        for (int k = 0; k < EMB; ++k) {
          const float xv = node_tab[tid*EMB + k];
          a = fmaf(xv, vs[k], a); d = fmaf(xv, vd[k], d);
        }
      }
      g_hs1[tid] = a; g_hd1[tid] = d;
    }
    return;
  }
  if (b <= 75) {                      // c2w / nw1 / ew1: 16384 each, 8 chunks
    const int grp = (b - 52) >> 3;
    const int chunk = (b - 52) & 7;
    const float* W = (grp == 0) ? c2_w : (grp == 1) ? n_w1 : e_w1;
    ushort_t* G = (grp == 0) ? g_c2w : (grp == 1) ? g_nw1 : g_ew1;
    const int base = chunk * 2048 + tid;
    #pragma unroll
    for (int it = 0; it < 8; ++it) {
      const int idx = base + it*256;
      const int j = idx & 7, l = (idx >> 3) & 63, r2 = idx >> 9;
      const int ks = r2 & 3, ct = r2 >> 2;
      const int row = ks*32 + (l >> 4)*8 + j;
      const int col = ct*16 + (l & 15);
      G[idx] = f2bf(W[row*HID + col]);
    }
    return;
  }
  if (b <= 82) {                      // nw2: 14336, 7 chunks
    const int base = (b - 76) * 2048 + tid;
    #pragma unroll
    for (int it = 0; it < 8; ++it) {
      const int idx = base + it*256;
      const int j = idx & 7, l = (idx >> 3) & 63, r2 = idx >> 9;
      const int ks = r2 & 3, ct = r2 >> 2;
      const int row = ks*32 + (l >> 4)*8 + j;
      const int col = ct*16 + (l & 15);
      g_nw2[idx] = (col < NOUT) ? f2bf(n_w2[row*NOUT + col]) : (ushort_t)0;
    }
    return;
  }
  {                                   // sw1t: 16384, 8 chunks
    const int base = (b - 83) * 2048 + tid;
    #pragma unroll
    for (int it = 0; it < 8; ++it) {
      const int idx = base + it*256;
      g_sw1t[idx] = s_w1[(idx & 127)*HID + (idx >> 7)];
    }
  }
}

// ---------------------------------------------------------------------------
// LDS map (bytes). Region R overlays Pf(64x64 f32) / Hr(64x136 ushort).
#define S_HC   0        // 128x72 ushort feat-major; reused as a1b 64x136 rows
#define S_R    18432    // max(Pf 16384, Hr 17408)
#define S_PART 35840    // 256 f32 (stop partials)
#define S_NS   36864    // 64 f32
#define S_ND   37120    // 64 f32
#define S_GP   37376    // 128 f32 (pool)
#define S_EBW  37888    // 256 f32: e_b1[0..127] | e_w2[0..127]
#define S_HCC  38912    // 8 f32
#define S_XS   38944    // 64 int
#define S_TOT  39200

__global__ __launch_bounds__(256, 4) void graph_kernel(
    const float* __restrict__ c1_b,
    const float* __restrict__ c2_as, const float* __restrict__ c2_ad,
    const float* __restrict__ c2_b,
    const float* __restrict__ s_b1,  const float* __restrict__ s_w2,
    const float* __restrict__ s_b2,
    const float* __restrict__ n_b1,  const float* __restrict__ n_b2,
    const float* __restrict__ e_b1,  const float* __restrict__ e_w2,
    const float* __restrict__ e_b2,
    const int* __restrict__ x,  const int* __restrict__ ei,
    const int* __restrict__ ea, const int* __restrict__ nedg,
    float* __restrict__ out)
{
  const int tid = threadIdx.x;
  const int gid = blockIdx.x;
  const int nb = gid * NPG;
  const int lane = tid & 63;
  const int wv = tid >> 6;
  const int qd = lane >> 4;        // quad
  const int cl = lane & 15;        // col/row-in-tile
  const int rb = wv * 16;          // wave's M-tile base row

  __shared__ __align__(16) char smem[S_TOT];
  ushort_t* Hc   = (ushort_t*)(smem + S_HC);   // [feat*72 + node]
  float*    Pf   = (float*)   (smem + S_R);    // 64x64 f32
  ushort_t* Hr   = (ushort_t*)(smem + S_R);    // stride 136 (row-major)
  float*    part = (float*)   (smem + S_PART);
  float*    ns   = (float*)   (smem + S_NS);
  float*    nd   = (float*)   (smem + S_ND);
  float*    gp   = (float*)   (smem + S_GP);
  float*    ebw  = (float*)   (smem + S_EBW);
  float*    hc   = (float*)   (smem + S_HCC);
  int*      xs   = (int*)     (smem + S_XS);
  ushort_t* a1b  = Hc;                         // 64x136 rows

  // ---- P0: edge regs, pair regs, xs -> ns/nd tables, zero Pf/gp, consts ----
  unsigned er[4];
  #pragma unroll
  for (int i = 0; i < 4; ++i) {
    const int k = tid + 256*i;
    const int s = ei[gid*EPG + k] - nb;
    const int d = ei[E_TOT + gid*EPG + k] - nb;
    const int t = ea[gid*EPG + k];
    er[i] = (unsigned)(s | (d << 6) | (t << 12));
  }
  const int2 prr = *(const int2*)(nedg + 2*(gid*NEPG + tid));
  if (tid < NPG) {
    const int cat = x[nb + tid];
    xs[tid] = cat;
    ns[tid] = g_hs1[cat];
    nd[tid] = g_hd1[cat];
  }
  {
    float4* pz = (float4*)Pf;
    #pragma unroll
    for (int j = 0; j < 4; ++j) pz[tid + j*256] = make_float4(0.f,0.f,0.f,0.f);
  }
  if (tid < 128) gp[tid] = 0.f;
  ebw[tid] = (tid < 128) ? e_b1[tid] : e_w2[tid - 128];
  if (tid < 8) hc[tid] = (tid < 4) ? g_he1[tid] : g_he2[tid-4];
  __syncthreads();                                        // B1

  // ---- E1+G: layer-1 edge pass (atomics) overlapped with nt1->Hc gather ----
  {
    const int gn = tid >> 2;
    const int f0 = (tid & 3) * 32;
    const ushort_t* srcp = g_nt1 + xs[gn]*HID + f0;
    const bf16x8 t0 = ((const bf16x8*)srcp)[0];
    const bf16x8 t1 = ((const bf16x8*)srcp)[1];
    const bf16x8 t2 = ((const bf16x8*)srcp)[2];
    const bf16x8 t3 = ((const bf16x8*)srcp)[3];
    #pragma unroll
    for (int i = 0; i < 4; ++i) {
      const unsigned tp = er[i];
      const int s = tp & 63, d = (tp >> 6) & 63, t = tp >> 12;
      float l = ns[s] + nd[d] + hc[t];
      l = (l > 0.f) ? l : 0.2f * l;
      atomicAdd(&Pf[d*64 + s], __expf(l));
    }
    #pragma unroll
    for (int q = 0; q < 8; ++q) {
      Hc[(f0 +      q)*72 + gn] = (ushort_t)t0[q];
      Hc[(f0 +  8 + q)*72 + gn] = (ushort_t)t1[q];
      Hc[(f0 + 16 + q)*72 + gn] = (ushort_t)t2[q];
      Hc[(f0 + 24 + q)*72 + gn] = (ushort_t)t3[q];
    }
  }
  __syncthreads();                                        // B2

  // ---- agg1 preload: P frags (f32->bf16 in-reg) + den rowsum ----
  bf16x8 pa0, pa1;
  float inv4[4];
  {
    const float* pr = Pf + (rb + cl)*64;
    const float4 v0 = *(const float4*)(pr + qd*8);
    const float4 v1 = *(const float4*)(pr + qd*8 + 4);
    const float4 v2 = *(const float4*)(pr + 32 + qd*8);
    const float4 v3 = *(const float4*)(pr + 36 + qd*8);
    pa0 = pk8(v0, v1); pa1 = pk8(v2, v3);
    float den = v0.x+v0.y+v0.z+v0.w + v1.x+v1.y+v1.z+v1.w
              + v2.x+v2.y+v2.z+v2.w + v3.x+v3.y+v3.z+v3.w;
    den += __shfl_xor(den, 16, 64);
    den += __shfl_xor(den, 32, 64);
    #pragma unroll
    for (int r = 0; r < 4; ++r)
      inv4[r] = 1.f / (__shfl(den, qd*4 + r, 64) + 1e-16f);
  }
  __syncthreads();                                        // B3

  // ---- agg1: h1 = relu(inv*(P@h1pre) + c1_b) -> Hr ----
  {
    #pragma unroll
    for (int ct = 0; ct < 8; ++ct) {
      f32x4 acc = {0.f, 0.f, 0.f, 0.f};
      const bf16x8 b0 = *(const bf16x8*)(Hc + (ct*16+cl)*72 + qd*8);
      const bf16x8 b1 = *(const bf16x8*)(Hc + (ct*16+cl)*72 + 32 + qd*8);
      acc = __builtin_amdgcn_mfma_f32_16x16x32_bf16(pa0, b0, acc, 0, 0, 0);
      acc = __builtin_amdgcn_mfma_f32_16x16x32_bf16(pa1, b1, acc, 0, 0, 0);
      const int n = ct*16 + cl;
      const float bias = c1_b[n];
      #pragma unroll
      for (int r = 0; r < 4; ++r)
        Hr[(rb + qd*4 + r)*136 + n] = f2bf(fmaxf(fmaf(acc[r], inv4[r], bias), 0.f));
    }
  }
  bf16x8 h1f[4];                     // wave-local rows, no barrier needed
  #pragma unroll
  for (int ks = 0; ks < 4; ++ks)
    h1f[ks] = *(const bf16x8*)(Hr + (rb+cl)*136 + ks*32 + qd*8);
  __syncthreads();                                        // B4

  // ---- P7: h2pre = h1 @ c2_w -> Hc + ns/nd; zero Pf ----
  {
    float4* pz = (float4*)Pf;
    #pragma unroll
    for (int j = 0; j < 4; ++j) pz[tid + j*256] = make_float4(0.f,0.f,0.f,0.f);
    float pns[4] = {0.f,0.f,0.f,0.f}, pnd[4] = {0.f,0.f,0.f,0.f};
    #pragma unroll
    for (int ct = 0; ct < 8; ++ct) {
      f32x4 acc = {0.f, 0.f, 0.f, 0.f};
      #pragma unroll
      for (int ks = 0; ks < 4; ++ks) {
        const bf16x8 b = *(const bf16x8*)(g_c2w + ((ct*4+ks)*64 + lane)*8);
        acc = __builtin_amdgcn_mfma_f32_16x16x32_bf16(h1f[ks], b, acc, 0, 0, 0);
      }
      const int n = ct*16 + cl;
      const float asv = c2_as[n], adv = c2_ad[n];
      #pragma unroll
      for (int r = 0; r < 4; ++r) {
        const float v = acc[r];
        Hc[n*72 + (rb + qd*4 + r)] = f2bf(v);
        pns[r] = fmaf(v, asv, pns[r]);
        pnd[r] = fmaf(v, adv, pnd[r]);
      }
    }
    #pragma unroll
    for (int r = 0; r < 4; ++r) {
      #pragma unroll
      for (int off = 1; off < 16; off <<= 1) {
        pns[r] += __shfl_xor(pns[r], off, 64);
        pnd[r] += __shfl_xor(pnd[r], off, 64);
      }
    }
    if (cl == 0) {
      #pragma unroll
      for (int r = 0; r < 4; ++r) { ns[rb+qd*4+r] = pns[r]; nd[rb+qd*4+r] = pnd[r]; }
    }
  }
  __syncthreads();                                        // B5

  // ---- edge pass 2 ----
  #pragma unroll
  for (int i = 0; i < 4; ++i) {
    const unsigned tp = er[i];
    const int s = tp & 63, d = (tp >> 6) & 63, t = tp >> 12;
    float l = ns[s] + nd[d] + hc[4 + t];
    l = (l > 0.f) ? l : 0.2f * l;
    atomicAdd(&Pf[d*64 + s], __expf(l));
  }
  __syncthreads();                                        // B6

  // ---- agg2 preload ----
  {
    const float* pr = Pf + (rb + cl)*64;
    const float4 v0 = *(const float4*)(pr + qd*8);
    const float4 v1 = *(const float4*)(pr + qd*8 + 4);
    const float4 v2 = *(const float4*)(pr + 32 + qd*8);
    const float4 v3 = *(const float4*)(pr + 36 + qd*8);
    pa0 = pk8(v0, v1); pa1 = pk8(v2, v3);
    float den = v0.x+v0.y+v0.z+v0.w + v1.x+v1.y+v1.z+v1.w
              + v2.x+v2.y+v2.z+v2.w + v3.x+v3.y+v3.z+v3.w;
    den += __shfl_xor(den, 16, 64);
    den += __shfl_xor(den, 32, 64);
    #pragma unroll
    for (int r = 0; r < 4; ++r)
      inv4[r] = 1.f / (__shfl(den, qd*4 + r, 64) + 1e-16f);
  }
  __syncthreads();                                        // B7

  // ---- agg2: h2 = inv*(P@h2pre) + c2_b -> Hr + pooling ----
  {
    #pragma unroll
    for (int ct = 0; ct < 8; ++ct) {
      f32x4 acc = {0.f, 0.f, 0.f, 0.f};
      const bf16x8 b0 = *(const bf16x8*)(Hc + (ct*16+cl)*72 + qd*8);
      const bf16x8 b1 = *(const bf16x8*)(Hc + (ct*16+cl)*72 + 32 + qd*8);
      acc = __builtin_amdgcn_mfma_f32_16x16x32_bf16(pa0, b0, acc, 0, 0, 0);
      acc = __builtin_amdgcn_mfma_f32_16x16x32_bf16(pa1, b1, acc, 0, 0, 0);
      const int n = ct*16 + cl;
      const float bias = c2_b[n];
      float colsum = 0.f;
      #pragma unroll
      for (int r = 0; r < 4; ++r) {
        const float v = fmaf(acc[r], inv4[r], bias);
        Hr[(rb + qd*4 + r)*136 + n] = f2bf(v);
        colsum += v;
      }
      colsum += __shfl_xor(colsum, 16, 64);
      colsum += __shfl_xor(colsum, 32, 64);
      if (qd == 0) atomicAdd(&gp[n], colsum);
    }
  }
  __syncthreads();                                        // B8

  // ---- stop head partials ----
  {
    const int j = tid & 127, half = tid >> 7;
    const float* wr = g_sw1t + j*HID + half*64;
    const float* gr = gp + half*64;
    float p = 0.f;
    #pragma unroll
    for (int q = 0; q < 16; ++q) {
      const float4 w = ((const float4*)wr)[q];
      const float4 g = ((const float4*)gr)[q];
      p = fmaf(w.x, g.x, p); p = fmaf(w.y, g.y, p);
      p = fmaf(w.z, g.z, p); p = fmaf(w.w, g.w, p);
    }
    part[tid] = p;
  }
  __syncthreads();                                        // B9

  // ---- post-B9: stop reduce (wave 0), fused addnode/addedge staging ----
  if (tid < 64) {
    const float z0 = fmaxf(part[tid] + part[tid+128] + s_b1[tid], 0.f);
    const float z1 = fmaxf(part[tid+64] + part[tid+192] + s_b1[tid+64], 0.f);
    float p = fmaf(z0, s_w2[tid], z1 * s_w2[tid+64]);
    #pragma unroll
    for (int off = 32; off > 0; off >>= 1) p += __shfl_down(p, off, 64);
    if (tid == 0) out[(size_t)gid*OUT_PG] = p + s_b2[0];
  }

  bf16x8 h2f[4];                    // own-wave h2 rows (agg2 wrote them)
  #pragma unroll
  for (int ks = 0; ks < 4; ++ks)
    h2f[ks] = *(const bf16x8*)(Hr + (rb+cl)*136 + ks*32 + qd*8);

  // fused: a1 = relu(h2@n_w1+n_b1) -> a1b(Hc);  u = h2@e_w1 -> Hr (own rows)
  {
    #pragma unroll
    for (int ct = 0; ct < 8; ++ct) {
      f32x4 an = {0.f, 0.f, 0.f, 0.f};
      f32x4 ae2 = {0.f, 0.f, 0.f, 0.f};
      #pragma unroll
      for (int ks = 0; ks < 4; ++ks) {
        const bf16x8 bn = *(const bf16x8*)(g_nw1 + ((ct*4+ks)*64 + lane)*8);
        const bf16x8 be = *(const bf16x8*)(g_ew1 + ((ct*4+ks)*64 + lane)*8);
        an  = __builtin_amdgcn_mfma_f32_16x16x32_bf16(h2f[ks], bn, an, 0, 0, 0);
        ae2 = __builtin_amdgcn_mfma_f32_16x16x32_bf16(h2f[ks], be, ae2, 0, 0, 0);
      }
      const int n = ct*16 + cl;
      const float bias = n_b1[n];
      #pragma unroll
      for (int r = 0; r < 4; ++r) {
        a1b[(rb + qd*4 + r)*136 + n] = f2bf(fmaxf(an[r] + bias, 0.f));
        Hr[(rb + qd*4 + r)*136 + n] = f2bf(ae2[r]);
      }
    }
  }
  // addnode head: out = a1 @ n_w2p + n_b2 (own-wave a1b rows)
  {
    bf16x8 af[4];
    #pragma unroll
    for (int ks = 0; ks < 4; ++ks)
      af[ks] = *(const bf16x8*)(a1b + (rb+cl)*136 + ks*32 + qd*8);
    float* ob = out + (size_t)gid*OUT_PG + 1;
    #pragma unroll
    for (int ct = 0; ct < 7; ++ct) {
      f32x4 acc = {0.f, 0.f, 0.f, 0.f};
      #pragma unroll
      for (int ks = 0; ks < 4; ++ks) {
        const bf16x8 b = *(const bf16x8*)(g_nw2 + ((ct*4+ks)*64 + lane)*8);
        acc = __builtin_amdgcn_mfma_f32_16x16x32_bf16(af[ks], b, acc, 0, 0, 0);
      }
      const int o = ct*16 + cl;
      if (o < NOUT) {
        const float b2 = n_b2[o];
        #pragma unroll
        for (int r = 0; r < 4; ++r)
          ob[(size_t)(rb + qd*4 + r)*NOUT + o] = acc[r] + b2;
      }
    }
  }
  __syncthreads();                                        // B10

  // ---- addedge pairs (u in Hr region) ----
  {
    const ushort_t* ui = Hr + (prr.x - nb)*136;
    const ushort_t* uj = Hr + (prr.y - nb)*136;
    float ssum = 0.f;
    #pragma unroll
    for (int q8 = 0; q8 < 16; ++q8) {
      const bf16x8 va = *(const bf16x8*)(ui + q8*8);
      const bf16x8 vb = *(const bf16x8*)(uj + q8*8);
      #pragma unroll
      for (int j = 0; j < 8; ++j) {
        const int c = q8*8 + j;
        float v = bf2f((ushort_t)va[j]) + bf2f((ushort_t)vb[j]) + ebw[c];
        v = fmaxf(v, 0.f);
        ssum = fmaf(v, ebw[128 + c], ssum);
      }
    }
    out[(size_t)gid*OUT_PG + 1 + NPG*NOUT + tid] = ssum + e_b2[0];
  }
}

// ---------------------------------------------------------------------------
extern "C" void kernel_launch(void* const* d_in, const int* in_sizes, int n_in,
                              void* d_out, int out_size, void* d_ws, size_t ws_size,
                              hipStream_t stream) {
  const float* node_tab = (const float*)d_in[0];
  const float* edge_tab = (const float*)d_in[1];
  const float* c1_w  = (const float*)d_in[2];
  const float* c1_we = (const float*)d_in[3];
  const float* c1_as = (const float*)d_in[4];
  const float* c1_ad = (const float*)d_in[5];
  const float* c1_ae = (const float*)d_in[6];
  const float* c1_b  = (const float*)d_in[7];
  const float* c2_w  = (const float*)d_in[8];
  const float* c2_we = (const float*)d_in[9];
  const float* c2_as = (const float*)d_in[10];
  const float* c2_ad = (const float*)d_in[11];
  const float* c2_ae = (const float*)d_in[12];
  const float* c2_b  = (const float*)d_in[13];
  const float* s_w1  = (const float*)d_in[14];
  const float* s_b1  = (const float*)d_in[15];
  const float* s_w2  = (const float*)d_in[16];
  const float* s_b2  = (const float*)d_in[17];
  const float* n_w1  = (const float*)d_in[18];
  const float* n_b1  = (const float*)d_in[19];
  const float* n_w2  = (const float*)d_in[20];
  const float* n_b2  = (const float*)d_in[21];
  const float* e_w1  = (const float*)d_in[22];
  const float* e_b1  = (const float*)d_in[23];
  const float* e_w2  = (const float*)d_in[24];
  const float* e_b2  = (const float*)d_in[25];
  const int* x    = (const int*)d_in[26];
  const int* ei   = (const int*)d_in[27];
  const int* ea   = (const int*)d_in[28];
  const int* nedg = (const int*)d_in[29];
  float* out = (float*)d_out;

  prep_kernel<<<dim3(91), dim3(256), 0, stream>>>(
      node_tab, edge_tab, c1_w, c1_we, c1_as, c1_ad, c1_ae,
      c2_w, c2_we, c2_ae, s_w1, n_w1, n_w2, e_w1);

  graph_kernel<<<dim3(B_GR), dim3(256), 0, stream>>>(
      c1_b, c2_as, c2_ad, c2_b, s_b1, s_w2, s_b2,
      n_b1, n_b2, e_b1, e_w2, e_b2, x, ei, ea, nedg, out);
}